// Round 4
// baseline (1828.261 us; speedup 1.0000x reference)
//
#include <hip/hip_runtime.h>

#define N_PTS 8192
#define KNN_K 24

__constant__ float c_omega[10] = {
  1.0f, 0.3981071705534972f, 0.15848931924611134f, 0.06309573444801933f,
  0.025118864315095794f, 0.01f, 0.003981071705534973f, 0.0015848931924611134f,
  0.0006309573444801933f, 0.00025118864315095795f
};

__device__ __forceinline__ unsigned keyOf(float f) {
  unsigned u = __float_as_uint(f);
  return (u & 0x80000000u) ? ~u : (u | 0x80000000u);
}

// ---------------- fc1: x = features @ fc1_w + fc1_b ----------------
__global__ __launch_bounds__(256) void fc1_kernel(
    const float* __restrict__ feat, const float* __restrict__ w,
    const float* __restrict__ bias, float* __restrict__ x) {
  int gid = blockIdx.x * 256 + threadIdx.x;   // B*N*128 total
  int row = gid >> 7, c = gid & 127;
  const float* f = feat + (size_t)row * 32;
  float acc = bias[c];
  #pragma unroll
  for (int j = 0; j < 32; ++j) acc = fmaf(f[j], w[j * 128 + c], acc);
  x[gid] = acc;
}

// ---------------- KNN: exact top-24 by (fp32 dist, idx) via 4-pass radix ----------------
__global__ __launch_bounds__(256) void knn_kernel(
    const float* __restrict__ xyz, int* __restrict__ knn) {
  __shared__ unsigned s_k[N_PTS];       // monotone keys of fp32 distances
  __shared__ unsigned s_hist[256];
  __shared__ unsigned s_scan[256];
  __shared__ int s_surv[64];
  __shared__ unsigned s_pref, s_rem, s_cnt;

  const int q = blockIdx.x;
  const int b = q >> 13, n = q & (N_PTS - 1);
  const int t = threadIdx.x;
  const float* xb = xyz + (size_t)b * N_PTS * 3;

  float qx = xb[n*3+0], qy = xb[n*3+1], qz = xb[n*3+2];
  // strict fp32 round-to-nearest, no fma — matches numpy association
  float sqq = __fadd_rn(__fadd_rn(__fmul_rn(qx,qx), __fmul_rn(qy,qy)), __fmul_rn(qz,qz));

  if (t == 0) { s_pref = 0u; s_rem = (unsigned)KNN_K; s_cnt = 0u; }
  __syncthreads();

  for (int j = 0; j < 32; ++j) {
    int m = t + 256 * j;
    float cx = xb[m*3+0], cy = xb[m*3+1], cz = xb[m*3+2];
    float sqc = __fadd_rn(__fadd_rn(__fmul_rn(cx,cx), __fmul_rn(cy,cy)), __fmul_rn(cz,cz));
    float dt  = __fadd_rn(__fadd_rn(__fmul_rn(qx,cx), __fmul_rn(qy,cy)), __fmul_rn(qz,cz));
    float d = __fsub_rn(__fadd_rn(sqq, sqc), __fmul_rn(2.0f, dt));
    s_k[m] = keyOf(d);
  }
  __syncthreads();

  // 4 radix passes, MSB->LSB: find exact key of 24th smallest (with duplicates)
  #pragma unroll
  for (int p = 3; p >= 0; --p) {
    unsigned pref = s_pref;
    unsigned rem = s_rem;
    __syncthreads();
    s_hist[t] = 0u;
    __syncthreads();
    int shift = 8 * p;
    for (int j = 0; j < 32; ++j) {
      int m = t + 256 * j;
      unsigned k = s_k[m];
      bool match = (p == 3) ? true : ((k >> (8 * (p + 1))) == (pref >> (8 * (p + 1))));
      if (match) atomicAdd(&s_hist[(k >> shift) & 255u], 1u);
    }
    __syncthreads();
    s_scan[t] = s_hist[t];
    __syncthreads();
    for (int off = 1; off < 256; off <<= 1) {
      unsigned cur = s_scan[t];
      unsigned add = (t >= off) ? s_scan[t - off] : 0u;
      __syncthreads();
      s_scan[t] = cur + add;
      __syncthreads();
    }
    {
      unsigned cum = s_scan[t];
      unsigned prev = (t > 0) ? s_scan[t - 1] : 0u;
      if (cum >= rem && prev < rem) {
        s_pref = pref | (((unsigned)t) << shift);
        s_rem = rem - prev;
      }
    }
    __syncthreads();
  }
  unsigned k24 = s_pref;   // exact key of the 24th smallest distance

  // capture all elements with key <= k24 (<=23 strictly below + ties; cap 64)
  for (int j = 0; j < 32; ++j) {
    int m = t + 256 * j;
    if (s_k[m] <= k24) {
      unsigned p = atomicAdd(&s_cnt, 1u);
      if (p < 64u) s_surv[p] = m;
    }
  }
  __syncthreads();

  if (t < 64) {
    unsigned cnt = s_cnt;
    int S = (int)((cnt < 64u) ? cnt : 64u);
    unsigned long long key = ~0ULL;
    if (t < S) {
      int m = s_surv[t];
      key = (((unsigned long long)s_k[m]) << 32) | (unsigned)m;
    }
    // 64-lane bitonic sort ascending by (dist-key, idx) — np's stable top_k order
    for (int size = 2; size <= 64; size <<= 1) {
      for (int stride = size >> 1; stride > 0; stride >>= 1) {
        unsigned long long pk = __shfl_xor(key, stride, 64);
        bool lower = (t & stride) == 0;
        bool up = (t & size) == 0;
        bool pLess = pk < key;
        bool take = (lower == up) ? pLess : !pLess;
        key = take ? pk : key;
      }
    }
    if (t < KNN_K) knn[(size_t)q * KNN_K + t] = (int)(key & 0xFFFFFFFFu);
  }
}

// ---------------- fused per-query edge pipeline ----------------
// out = act(in[24x128] @ Wg[128x128] + bg), weights staged through sW in 32-row chunks
__device__ __forceinline__ void gemm24x128(
    const float* __restrict__ inL, const float* __restrict__ Wg,
    const float* __restrict__ bg, float* __restrict__ outL,
    float* __restrict__ sW, int t, bool doRelu) {
  const int cg = t & 31, eg = t >> 5;
  const int c0 = cg * 4, e0 = eg * 3;
  float4 bias = *(const float4*)&bg[c0];
  float acc[3][4];
  #pragma unroll
  for (int r = 0; r < 3; ++r) {
    acc[r][0] = bias.x; acc[r][1] = bias.y; acc[r][2] = bias.z; acc[r][3] = bias.w;
  }
  #pragma unroll
  for (int h = 0; h < 4; ++h) {
    for (int i = t * 4; i < 4096; i += 1024)
      *(float4*)&sW[i] = *(const float4*)&Wg[h * 4096 + i];
    __syncthreads();
    #pragma unroll 8
    for (int j = 0; j < 32; ++j) {
      float4 w = *(float4*)&sW[j * 128 + c0];
      #pragma unroll
      for (int r = 0; r < 3; ++r) {
        float p = inL[(e0 + r) * 128 + h * 32 + j];
        acc[r][0] = fmaf(p, w.x, acc[r][0]);
        acc[r][1] = fmaf(p, w.y, acc[r][1]);
        acc[r][2] = fmaf(p, w.z, acc[r][2]);
        acc[r][3] = fmaf(p, w.w, acc[r][3]);
      }
    }
    __syncthreads();
  }
  #pragma unroll
  for (int r = 0; r < 3; ++r) {
    float4 o;
    o.x = doRelu ? fmaxf(acc[r][0], 0.f) : acc[r][0];
    o.y = doRelu ? fmaxf(acc[r][1], 0.f) : acc[r][1];
    o.z = doRelu ? fmaxf(acc[r][2], 0.f) : acc[r][2];
    o.w = doRelu ? fmaxf(acc[r][3], 0.f) : acc[r][3];
    *(float4*)&outL[(e0 + r) * 128 + c0] = o;
  }
  __syncthreads();
}

__global__ __launch_bounds__(256) void edge_kernel(
    const float* __restrict__ xyz, const float* __restrict__ x,
    const int* __restrict__ knn,
    const float* __restrict__ d1w, const float* __restrict__ d1b,
    const float* __restrict__ d2w, const float* __restrict__ d2b,
    const float* __restrict__ g1w, const float* __restrict__ g1b,
    const float* __restrict__ g2w, const float* __restrict__ g2b,
    const float* __restrict__ fc2w, const float* __restrict__ fc2b,
    float* __restrict__ out_res, float* __restrict__ out_attn) {
  __shared__ float sW[32 * 128];   // 16 KB weight staging chunk
  __shared__ float sA[24 * 128];   // v, then v+pos_enc
  __shared__ float sB[24 * 128];   // pos_enc, then h1
  __shared__ float sC[24 * 128];   // h-relu, then u, then logits/probs
  __shared__ float sPE[24 * 64];   // pe (60 cols, padded)
  __shared__ float sXQ[128];
  __shared__ float sR[128];
  __shared__ int sIdx[KNN_K];
  __shared__ float sG[24 * 4];

  const int q = blockIdx.x;
  const int b = q >> 13, n = q & (N_PTS - 1);
  const int t = threadIdx.x;
  const float* xb = xyz + (size_t)b * N_PTS * 3;
  const float* xfb = x + (size_t)b * N_PTS * 128;

  if (t < KNN_K) sIdx[t] = knn[(size_t)q * KNN_K + t] & (N_PTS - 1);  // clamp: finite on any bug
  if (t >= 128) sXQ[t - 128] = xfb[(size_t)n * 128 + (t - 128)];
  __syncthreads();
  if (t < 72) {
    int e = t / 3, c = t - e * 3;
    sG[e * 4 + c] = xb[n * 3 + c] - xb[sIdx[e] * 3 + c];
  }
  for (int i = t; i < 24 * 128; i += 256) {
    int e = i >> 7;
    sA[i] = xfb[(size_t)sIdx[e] * 128 + (i & 127)];
  }
  __syncthreads();
  // positional encoding: [24][60], layout c*20 + (cos?10:0) + j
  for (int i = t; i < 24 * 60; i += 256) {
    int e = i / 60, r = i - e * 60;
    int c = r / 20, inner = r - c * 20;
    int jj = (inner >= 10) ? inner - 10 : inner;
    float v = sG[e * 4 + c] * c_omega[jj];
    sPE[e * 64 + r] = (inner >= 10) ? __cosf(v) : __sinf(v);
  }
  __syncthreads();

  // stage 1: sC = relu(sPE @ d1w + d1b), K = 60 (chunks 32 + 28)
  {
    const int cg = t & 31, eg = t >> 5;
    const int c0 = cg * 4, e0 = eg * 3;
    float4 bias = *(const float4*)&d1b[c0];
    float acc[3][4];
    #pragma unroll
    for (int r = 0; r < 3; ++r) {
      acc[r][0] = bias.x; acc[r][1] = bias.y; acc[r][2] = bias.z; acc[r][3] = bias.w;
    }
    #pragma unroll
    for (int h = 0; h < 2; ++h) {
      int rows = h ? 28 : 32;
      for (int i = t * 4; i < rows * 128; i += 1024)
        *(float4*)&sW[i] = *(const float4*)&d1w[h * 4096 + i];
      __syncthreads();
      for (int j = 0; j < rows; ++j) {
        float4 w = *(float4*)&sW[j * 128 + c0];
        #pragma unroll
        for (int r = 0; r < 3; ++r) {
          float p = sPE[(e0 + r) * 64 + h * 32 + j];
          acc[r][0] = fmaf(p, w.x, acc[r][0]);
          acc[r][1] = fmaf(p, w.y, acc[r][1]);
          acc[r][2] = fmaf(p, w.z, acc[r][2]);
          acc[r][3] = fmaf(p, w.w, acc[r][3]);
        }
      }
      __syncthreads();
    }
    #pragma unroll
    for (int r = 0; r < 3; ++r) {
      float4 o = make_float4(fmaxf(acc[r][0], 0.f), fmaxf(acc[r][1], 0.f),
                             fmaxf(acc[r][2], 0.f), fmaxf(acc[r][3], 0.f));
      *(float4*)&sC[(e0 + r) * 128 + c0] = o;
    }
    __syncthreads();
  }

  // stage 2: sB = sC @ d2w + d2b  (pos_enc)
  gemm24x128(sC, d2w, d2b, sB, sW, t, false);

  // u = xq - v + pos_enc -> sC ; sA = v + pos_enc
  for (int i = t; i < 24 * 128; i += 256) {
    int dd = i & 127;
    float vv = sA[i], pp = sB[i];
    sC[i] = sXQ[dd] - vv + pp;
    sA[i] = vv + pp;
  }
  __syncthreads();

  // stage 3: sB = relu(sC @ g1w + g1b)
  gemm24x128(sC, g1w, g1b, sB, sW, t, true);
  // stage 4: sC = sB @ g2w + g2b  (logits)
  gemm24x128(sB, g2w, g2b, sC, sW, t, false);

  // softmax over K per column + res accumulation
  if (t < 128) {
    const float scale = 0.08838834764831845f;  // 1/sqrt(128)
    float mx = -3.0e38f;
    #pragma unroll
    for (int e = 0; e < KNN_K; ++e) mx = fmaxf(mx, sC[e * 128 + t] * scale);
    float s = 0.f;
    #pragma unroll
    for (int e = 0; e < KNN_K; ++e) {
      float ex = __expf(sC[e * 128 + t] * scale - mx);
      sC[e * 128 + t] = ex;
      s += ex;
    }
    float inv = 1.0f / s;
    float r = 0.f;
    size_t base = (size_t)q * KNN_K * 128 + t;
    #pragma unroll
    for (int e = 0; e < KNN_K; ++e) {
      float p = sC[e * 128 + t] * inv;
      out_attn[base + (size_t)e * 128] = p;
      r = fmaf(p, sA[e * 128 + t], r);
    }
    sR[t] = r;
  }
  __syncthreads();

  // final: out_res = sR @ fc2w + fc2b + xq
  float accf = 0.f;
  #pragma unroll
  for (int h = 0; h < 4; ++h) {
    for (int i = t * 4; i < 4096; i += 1024)
      *(float4*)&sW[i] = *(const float4*)&fc2w[h * 4096 + i];
    __syncthreads();
    if (t < 128) {
      #pragma unroll 8
      for (int j = 0; j < 32; ++j)
        accf = fmaf(sR[h * 32 + j], sW[j * 128 + t], accf);
    }
    __syncthreads();
  }
  if (t < 128)
    out_res[(size_t)q * 128 + t] = accf + fc2b[t] + sXQ[t];
}

extern "C" void kernel_launch(void* const* d_in, const int* in_sizes, int n_in,
                              void* d_out, int out_size, void* d_ws, size_t ws_size,
                              hipStream_t stream) {
  const float* feat = (const float*)d_in[0];
  const float* xyz  = (const float*)d_in[1];
  const float* fc1w = (const float*)d_in[2];
  const float* fc1b = (const float*)d_in[3];
  const float* fc2w = (const float*)d_in[4];
  const float* fc2b = (const float*)d_in[5];
  const float* d1w  = (const float*)d_in[6];
  const float* d1b  = (const float*)d_in[7];
  const float* d2w  = (const float*)d_in[8];
  const float* d2b  = (const float*)d_in[9];
  const float* g1w  = (const float*)d_in[10];
  const float* g1b  = (const float*)d_in[11];
  const float* g2w  = (const float*)d_in[12];
  const float* g2b  = (const float*)d_in[13];

  float* x = (float*)d_ws;                                        // 2*8192*128 fp32 = 8 MB
  int* knn = (int*)((char*)d_ws + (size_t)2 * 8192 * 128 * 4);    // 2*8192*24 int32

  float* out_res  = (float*)d_out;                                // [2,8192,128] fp32
  float* out_attn = out_res + (size_t)2 * 8192 * 128;             // [2,8192,24,128] fp32

  fc1_kernel<<<dim3((2 * 8192 * 128) / 256), 256, 0, stream>>>(feat, fc1w, fc1b, x);
  knn_kernel<<<dim3(2 * 8192), 256, 0, stream>>>(xyz, knn);
  edge_kernel<<<dim3(2 * 8192), 256, 0, stream>>>(xyz, x, knn,
                                                  d1w, d1b, d2w, d2b,
                                                  g1w, g1b, g2w, g2b,
                                                  fc2w, fc2b, out_res, out_attn);
}